// Round 2
// baseline (396.395 us; speedup 1.0000x reference)
//
#include <hip/hip_runtime.h>
#include <stdint.h>

#define UU 512
#define NHEAD 8
#define CHK 64
#define NB 8
#define NXX 1024
#define NYY 1024
#define SCALE_F 0.125f   // 1/sqrt(64)

typedef __bf16 bf16x8 __attribute__((ext_vector_type(8)));
typedef float f32x4 __attribute__((ext_vector_type(4)));
typedef unsigned short us4 __attribute__((ext_vector_type(4)));

__device__ __forceinline__ unsigned short f2bf(float f) {
  union { float f; uint32_t u; } v; v.f = f;
  return (unsigned short)((v.u + 0x7FFFu + ((v.u >> 16) & 1u)) >> 16);
}

// ---------------------------------------------------------------------------
// Mask dtype probe: u8 bool -> nonzero bytes at p%4==1; f32 1.0f -> nonzero at
// p%4==3 only; int32 0/1 -> neither.
__global__ void detect_mask(const unsigned char* __restrict__ m, int* __restrict__ det) {
  int t = threadIdx.x;
  int c1 = 0, c3 = 0;
  for (int q = t; q < 16384; q += 256) {
    c1 |= m[q * 4 + 1];
    c3 |= m[q * 4 + 3];
  }
  if (c1) atomicOr(&det[0], 1);
  if (c3) atomicOr(&det[1], 1);
}

// ---------------------------------------------------------------------------
__global__ void cast_w(const float* __restrict__ W, unsigned short* __restrict__ Wb) {
  int i = blockIdx.x * 256 + threadIdx.x;
  Wb[i] = f2bf(W[i]);
}

// ---------------------------------------------------------------------------
// xt[bz][n][i] (bf16) = src[b][i][n].  Block: 64i x 64n sub-tile, 4 i-subtiles.
__global__ __launch_bounds__(256) void transpose_cast(
    const float* __restrict__ x, const float* __restrict__ y,
    unsigned short* __restrict__ tr) {
  __shared__ float tile[64][68];
  int nt = blockIdx.x, itq = blockIdx.y, bz = blockIdx.z;
  int b = bz & 7;
  const float* src = (bz >> 3) ? y : x;
  int t = threadIdx.x;
#pragma unroll
  for (int sub = 0; sub < 4; sub++) {
    int it = itq * 4 + sub;
    const float* base = src + ((size_t)b * UU + it * 64) * NXX + nt * 64;
    int c4 = (t & 15) * 4;
#pragma unroll
    for (int p = 0; p < 4; p++) {
      int i = (t >> 4) + p * 16;
      *(float4*)&tile[i][c4] = *(const float4*)(base + (size_t)i * NXX + c4);
    }
    __syncthreads();
    unsigned short* ob = tr + ((size_t)bz * NXX + nt * 64) * UU + it * 64;
    int n = t & 63, iq = t >> 6;
#pragma unroll
    for (int g = 0; g < 4; g++) {
      int i0 = iq * 16 + g * 4;
      us4 pk;
      pk.x = f2bf(tile[i0 + 0][n]);
      pk.y = f2bf(tile[i0 + 1][n]);
      pk.z = f2bf(tile[i0 + 2][n]);
      pk.w = f2bf(tile[i0 + 3][n]);
      *(us4*)(ob + (size_t)n * UU + i0) = pk;
    }
    __syncthreads();
  }
}

// ---------------------------------------------------------------------------
// cv[bz][n][u] = sum_i W[u][i] * xt[bz][n][i].  Block: 128n x 64u, waves 2x2.
__global__ __launch_bounds__(256) void conv_gemm(
    const unsigned short* __restrict__ tr, const unsigned short* __restrict__ Wb,
    unsigned short* __restrict__ cv) {
  int fl = blockIdx.x;
  int bz = fl & 15, r2 = fl >> 4;
  int nt = r2 & 7, ut = r2 >> 3;
  int t = threadIdx.x, w = t >> 6, l = t & 63;
  int lane_m = l & 15, lane_g = l >> 4;
  int wr = w >> 1, wc = w & 1;
  int n_base = nt * 128 + wr * 64, u_base = ut * 64 + wc * 32;
  const unsigned short* xb = tr + (size_t)bz * NXX * UU;
  f32x4 acc[4][2] = {};
  for (int kb = 0; kb < 16; kb++) {
    int k = kb * 32 + lane_g * 8;
    bf16x8 a[2], bf[4];
#pragma unroll
    for (int tm = 0; tm < 2; tm++)
      a[tm] = *(const bf16x8*)(Wb + (size_t)(u_base + tm * 16 + lane_m) * UU + k);
#pragma unroll
    for (int tn = 0; tn < 4; tn++)
      bf[tn] = *(const bf16x8*)(xb + (size_t)(n_base + tn * 16 + lane_m) * UU + k);
#pragma unroll
    for (int tn = 0; tn < 4; tn++)
#pragma unroll
      for (int tm = 0; tm < 2; tm++)
        acc[tn][tm] = __builtin_amdgcn_mfma_f32_16x16x32_bf16(a[tm], bf[tn], acc[tn][tm], 0, 0, 0);
  }
  unsigned short* ob = cv + (size_t)bz * NXX * UU;
#pragma unroll
  for (int tn = 0; tn < 4; tn++)
#pragma unroll
    for (int tm = 0; tm < 2; tm++) {
      int n = n_base + tn * 16 + lane_m;
      int u = u_base + tm * 16 + 4 * lane_g;
      us4 pk;
      pk.x = f2bf(acc[tn][tm][0]); pk.y = f2bf(acc[tn][tm][1]);
      pk.z = f2bf(acc[tn][tm][2]); pk.w = f2bf(acc[tn][tm][3]);
      *(us4*)(ob + (size_t)n * UU + u) = pk;
    }
}

// ---------------------------------------------------------------------------
// Block: 128n x 64m, ALL 8 heads. Wave w owns rows n0+w*32..+32.
// Mask held in 32 regs (C/D fragment layout), reused across all 8 heads.
__global__ __launch_bounds__(256) void score_kernel(
    const unsigned short* __restrict__ cv, const void* __restrict__ maskp,
    const int* __restrict__ det, float* __restrict__ sim,
    unsigned int* __restrict__ cnt) {
  int fl = blockIdx.x;
  int b = fl & 7, r2 = fl >> 3;
  int nt = r2 & 7, mt = r2 >> 3;          // nt 0..7 (128-row tiles), mt 0..15
  int t = threadIdx.x, w = t >> 6, l = t & 63;
  int lane_m = l & 15, lane_g = l >> 4;
  int n0 = nt * 128 + w * 32, m0 = mt * 64;

  int mode = det[0] ? 0 : (det[1] ? 2 : 1);  // 0=u8, 1=i32, 2=f32 (uniform)
  float mreg[2][4][4];
  unsigned int cnt_loc = 0;
#pragma unroll
  for (int tn = 0; tn < 2; tn++)
#pragma unroll
    for (int r = 0; r < 4; r++)
#pragma unroll
      for (int tm = 0; tm < 4; tm++) {
        int nn = n0 + tn * 16 + 4 * lane_g + r;
        int mm = m0 + tm * 16 + lane_m;
        size_t idx = ((size_t)b * NXX + nn) * NYY + mm;
        int v;
        if (mode == 0)      v = ((const unsigned char*)maskp)[idx] != 0;
        else if (mode == 1) v = ((const int*)maskp)[idx] != 0;
        else                v = ((const float*)maskp)[idx] != 0.0f;
        mreg[tn][tm][r] = (float)v;
        cnt_loc += (unsigned)v;
      }
  for (int s = 1; s < 64; s <<= 1) cnt_loc += __shfl_xor(cnt_loc, s);
  if (l == 0) atomicAdd(&cnt[b], cnt_loc);

  const unsigned short* xb = cv + ((size_t)b * NXX + n0) * UU;
  const unsigned short* yb = cv + ((size_t)(NB + b) * NYY + m0) * UU;
#pragma unroll
  for (int h = 0; h < NHEAD; h++) {
    int co = h * CHK;
    bf16x8 afr[2][2], bfr[4][2];
#pragma unroll
    for (int tn = 0; tn < 2; tn++)
#pragma unroll
      for (int kb = 0; kb < 2; kb++)
        afr[tn][kb] = *(const bf16x8*)(xb + (size_t)(tn * 16 + lane_m) * UU + co + kb * 32 + lane_g * 8);
#pragma unroll
    for (int tm = 0; tm < 4; tm++)
#pragma unroll
      for (int kb = 0; kb < 2; kb++)
        bfr[tm][kb] = *(const bf16x8*)(yb + (size_t)(tm * 16 + lane_m) * UU + co + kb * 32 + lane_g * 8);
    float hs = 0.f;
#pragma unroll
    for (int tn = 0; tn < 2; tn++)
#pragma unroll
      for (int tm = 0; tm < 4; tm++) {
        f32x4 acc = {};
        acc = __builtin_amdgcn_mfma_f32_16x16x32_bf16(afr[tn][0], bfr[tm][0], acc, 0, 0, 0);
        acc = __builtin_amdgcn_mfma_f32_16x16x32_bf16(afr[tn][1], bfr[tm][1], acc, 0, 0, 0);
#pragma unroll
        for (int r = 0; r < 4; r++) {
          float v = acc[r];
          v = v > 0.f ? v : 0.f;
          hs = fmaf(v, mreg[tn][tm][r], hs);
        }
      }
    for (int s = 1; s < 64; s <<= 1) hs += __shfl_xor(hs, s);
    if (l == 0) atomicAdd(&sim[b * NHEAD + h], hs);
  }
}

// ---------------------------------------------------------------------------
__global__ void finalize(const float* __restrict__ sim, const unsigned int* __restrict__ cnt,
                         const float* __restrict__ fcw, const float* __restrict__ fcb,
                         float* __restrict__ out) {
  int b = threadIdx.x;
  if (b < NB) {
    float s = 0.f;
#pragma unroll
    for (int h = 0; h < NHEAD; h++) s += sim[b * NHEAD + h] * fcw[h];
    unsigned int n = cnt[b];
    if (n == 0) n = 1;
    out[b] = s * (SCALE_F / (float)n) + fcb[0];
  }
}

// ---------------------------------------------------------------------------
extern "C" void kernel_launch(void* const* d_in, const int* in_sizes, int n_in,
                              void* d_out, int out_size, void* d_ws, size_t ws_size,
                              hipStream_t stream) {
  const float* x = (const float*)d_in[0];
  const float* y = (const float*)d_in[1];
  const void* mask = d_in[2];
  const float* W = (const float*)d_in[3];
  const float* fcw = (const float*)d_in[4];
  const float* fcb = (const float*)d_in[5];
  float* out = (float*)d_out;
  char* ws = (char*)d_ws;

  unsigned short* tr = (unsigned short*)ws;                  // [2*8][1024][512] bf16
  unsigned short* cv = (unsigned short*)(ws + (16u << 20));  // [2*8][1024][512] bf16
  unsigned short* Wb = (unsigned short*)(ws + (32u << 20));  // [512][512] bf16
  char* st = ws + (32u << 20) + (1u << 19);
  float* sim = (float*)st;             // 64 f32
  unsigned int* cnt = (unsigned int*)(st + 256);  // 8 u32
  int* det = (int*)(st + 288);         // 2 i32

  hipMemsetAsync(st, 0, 512, stream);
  detect_mask<<<1, 256, 0, stream>>>((const unsigned char*)mask, det);
  cast_w<<<1024, 256, 0, stream>>>(W, Wb);
  transpose_cast<<<dim3(16, 2, 16), 256, 0, stream>>>(x, y, tr);
  conv_gemm<<<1024, 256, 0, stream>>>(tr, Wb, cv);
  score_kernel<<<1024, 256, 0, stream>>>(cv, mask, det, sim, cnt);
  finalize<<<1, 64, 0, stream>>>(sim, cnt, fcw, fcb, out);
}

// Round 3
// 384.176 us; speedup vs baseline: 1.0318x; 1.0318x over previous
//
#include <hip/hip_runtime.h>
#include <stdint.h>

#define UU 512
#define NHEAD 8
#define NB 8
#define NXX 1024
#define NYY 1024
#define SCALE_F 0.125f   // 1/sqrt(64)

typedef __bf16 bf16x8 __attribute__((ext_vector_type(8)));
typedef float f32x4 __attribute__((ext_vector_type(4)));
typedef unsigned short us4 __attribute__((ext_vector_type(4)));

__device__ __forceinline__ unsigned short f2bf(float f) {
  union { float f; uint32_t u; } v; v.f = f;
  return (unsigned short)((v.u + 0x7FFFu + ((v.u >> 16) & 1u)) >> 16);
}

// ---------------------------------------------------------------------------
// Mask dtype probe: u8 bool -> nonzero bytes at p%4==1; f32 1.0f -> nonzero at
// p%4==3 only; int32 0/1 -> neither.
__global__ void detect_mask(const unsigned char* __restrict__ m, int* __restrict__ det) {
  int t = threadIdx.x;
  int c1 = 0, c3 = 0;
  for (int q = t; q < 16384; q += 256) {
    c1 |= m[q * 4 + 1];
    c3 |= m[q * 4 + 3];
  }
  if (c1) atomicOr(&det[0], 1);
  if (c3) atomicOr(&det[1], 1);
}

// ---------------------------------------------------------------------------
__global__ void cast_w(const float* __restrict__ W, unsigned short* __restrict__ Wb) {
  int i = blockIdx.x * 256 + threadIdx.x;
  Wb[i] = f2bf(W[i]);
}

// ---------------------------------------------------------------------------
// Fused transpose+cast+GEMM: cv[bz][n][u] = sum_i W[u][i] * src[b][i][n].
// Block owns (bz, 32 n-rows), computes all 512 u. x-tile staged into LDS as
// transposed bf16 with XOR swizzle: elem(n,i) at n*512 + (i ^ ((n&7)<<3)).
__global__ __launch_bounds__(256, 3) void conv_fused(
    const float* __restrict__ x, const float* __restrict__ y,
    const unsigned short* __restrict__ Wb, unsigned short* __restrict__ cv) {
  __shared__ unsigned short bs[32 * 512];  // 32 KB
  int fl = blockIdx.x;
  int bz = fl & 15, nt = fl >> 4;          // nt 0..31
  int b = bz & 7;
  const float* src = (bz >> 3) ? y : x;
  int n0 = nt * 32;
  int t = threadIdx.x;

  // stage: each thread reads 2 consecutive i-rows x 4 n (2x float4), packs
  // bf16 pairs along i, writes ds_write_b32.
  {
    int cq = (t & 7) * 4;
    int i2b = (t >> 3) * 2;
    const float* gb = src + (size_t)b * UU * NXX + n0 + cq;
#pragma unroll
    for (int it = 0; it < 8; it++) {
      int i2 = i2b + it * 64;
      float4 va = *(const float4*)(gb + (size_t)i2 * NXX);
      float4 vb = *(const float4*)(gb + (size_t)(i2 + 1) * NXX);
#pragma unroll
      for (int j = 0; j < 4; j++) {
        int n = cq + j;
        unsigned int pk = (unsigned int)f2bf(((const float*)&va)[j])
                        | ((unsigned int)f2bf(((const float*)&vb)[j]) << 16);
        int e = n * 512 + (i2 ^ ((n & 7) << 3));   // even
        *(unsigned int*)&bs[e] = pk;
      }
    }
  }
  __syncthreads();

  int w = t >> 6, l = t & 63;
  int lane_m = l & 15, lane_g = l >> 4;
  int u0 = w * 128;
  f32x4 acc[2][8] = {};
  for (int kb = 0; kb < 16; kb++) {
    int k = kb * 32 + lane_g * 8;
    bf16x8 a[8], bb[2];
#pragma unroll
    for (int tu = 0; tu < 8; tu++)
      a[tu] = *(const bf16x8*)(Wb + (size_t)(u0 + tu * 16 + lane_m) * UU + k);
#pragma unroll
    for (int tn = 0; tn < 2; tn++) {
      int nl = tn * 16 + lane_m;
      bb[tn] = *(const bf16x8*)&bs[nl * 512 + (k ^ ((nl & 7) << 3))];
    }
#pragma unroll
    for (int tn = 0; tn < 2; tn++)
#pragma unroll
      for (int tu = 0; tu < 8; tu++)
        acc[tn][tu] = __builtin_amdgcn_mfma_f32_16x16x32_bf16(a[tu], bb[tn], acc[tn][tu], 0, 0, 0);
  }
  unsigned short* ob = cv + (size_t)bz * NXX * UU;
#pragma unroll
  for (int tn = 0; tn < 2; tn++)
#pragma unroll
    for (int tu = 0; tu < 8; tu++) {
      int n = n0 + tn * 16 + lane_m;
      int u = u0 + tu * 16 + 4 * lane_g;
      us4 pk;
      pk.x = f2bf(acc[tn][tu][0]); pk.y = f2bf(acc[tn][tu][1]);
      pk.z = f2bf(acc[tn][tu][2]); pk.w = f2bf(acc[tn][tu][3]);
      *(us4*)(ob + (size_t)n * UU + u) = pk;
    }
}

// ---------------------------------------------------------------------------
// Block: (b, 64n, 64m), ALL 8 heads. Wave w: n-half (w&1), head-half (w>>1).
// Mask: coalesced 16B stage -> LDS f32 -> 32 regs per wave, reused 4 heads.
// Reductions hoisted out of the head loop.
__global__ __launch_bounds__(256, 3) void score_kernel(
    const unsigned short* __restrict__ cv, const void* __restrict__ maskp,
    const int* __restrict__ det, float* __restrict__ sim,
    unsigned int* __restrict__ cnt) {
  __shared__ float mf[64][68];
  int fl = blockIdx.x;
  int b = fl & 7, rr = fl >> 3;
  int nt = rr & 15, mt = rr >> 4;
  int t = threadIdx.x, w = t >> 6, l = t & 63;
  int lane_m = l & 15, lane_g = l >> 4;
  int n0 = nt * 64, m0 = mt * 64;

  int is_u8 = det[0] != 0;   // else 4-byte elems (i32 or f32): nonzero-bits test
  unsigned int cl = 0;
  {
    int row = t >> 2, cq = (t & 3) * 16;
    size_t eb = ((size_t)b * NXX + n0 + row) * NYY + m0 + cq;
    if (is_u8) {
      uint4 v = *(const uint4*)((const unsigned char*)maskp + eb);
#pragma unroll
      for (int j = 0; j < 16; j++) {
        unsigned int word = ((const unsigned int*)&v)[j >> 2];
        int bit = ((word >> ((j & 3) * 8)) & 0xffu) != 0;
        mf[row][cq + j] = (float)bit;
        cl += (unsigned)bit;
      }
    } else {
      const unsigned int* mp = (const unsigned int*)maskp + eb;
#pragma unroll
      for (int q = 0; q < 4; q++) {
        uint4 v = *(const uint4*)(mp + q * 4);
        unsigned int ws[4] = {v.x, v.y, v.z, v.w};
#pragma unroll
        for (int j = 0; j < 4; j++) {
          int bit = ws[j] != 0;
          mf[row][cq + q * 4 + j] = (float)bit;
          cl += (unsigned)bit;
        }
      }
    }
  }
  for (int s = 1; s < 64; s <<= 1) cl += __shfl_xor(cl, s);
  if (l == 0) atomicAdd(&cnt[b], cl);
  __syncthreads();

  int nw0 = (w & 1) * 32;
  float mreg[2][4][4];
#pragma unroll
  for (int tn = 0; tn < 2; tn++)
#pragma unroll
    for (int tm = 0; tm < 4; tm++)
#pragma unroll
      for (int r = 0; r < 4; r++)
        mreg[tn][tm][r] = mf[nw0 + tn * 16 + 4 * lane_g + r][tm * 16 + lane_m];

  const unsigned short* xb = cv + ((size_t)b * NXX + n0 + nw0) * UU;
  const unsigned short* yb = cv + ((size_t)(NB + b) * NYY + m0) * UU;
  float hsv[4] = {0.f, 0.f, 0.f, 0.f};
#pragma unroll
  for (int hh = 0; hh < 4; hh++) {
    int co = ((w >> 1) * 4 + hh) * 64;
    bf16x8 afr[2][2], bfr[4][2];
#pragma unroll
    for (int tn = 0; tn < 2; tn++)
#pragma unroll
      for (int kb = 0; kb < 2; kb++)
        afr[tn][kb] = *(const bf16x8*)(xb + (size_t)(tn * 16 + lane_m) * UU + co + kb * 32 + lane_g * 8);
#pragma unroll
    for (int tm = 0; tm < 4; tm++)
#pragma unroll
      for (int kb = 0; kb < 2; kb++)
        bfr[tm][kb] = *(const bf16x8*)(yb + (size_t)(tm * 16 + lane_m) * UU + co + kb * 32 + lane_g * 8);
#pragma unroll
    for (int tn = 0; tn < 2; tn++)
#pragma unroll
      for (int tm = 0; tm < 4; tm++) {
        f32x4 acc = {};
        acc = __builtin_amdgcn_mfma_f32_16x16x32_bf16(afr[tn][0], bfr[tm][0], acc, 0, 0, 0);
        acc = __builtin_amdgcn_mfma_f32_16x16x32_bf16(afr[tn][1], bfr[tm][1], acc, 0, 0, 0);
#pragma unroll
        for (int r = 0; r < 4; r++) {
          float v = acc[r];
          v = v > 0.f ? v : 0.f;
          hsv[hh] = fmaf(v, mreg[tn][tm][r], hsv[hh]);
        }
      }
  }
#pragma unroll
  for (int hh = 0; hh < 4; hh++) {
    float hs = hsv[hh];
    for (int s = 1; s < 64; s <<= 1) hs += __shfl_xor(hs, s);
    if (l == 0) atomicAdd(&sim[b * NHEAD + (w >> 1) * 4 + hh], hs);
  }
}

// ---------------------------------------------------------------------------
__global__ void finalize(const float* __restrict__ sim, const unsigned int* __restrict__ cnt,
                         const float* __restrict__ fcw, const float* __restrict__ fcb,
                         float* __restrict__ out) {
  int b = threadIdx.x;
  if (b < NB) {
    float s = 0.f;
#pragma unroll
    for (int h = 0; h < NHEAD; h++) s += sim[b * NHEAD + h] * fcw[h];
    unsigned int n = cnt[b];
    if (n == 0) n = 1;
    out[b] = s * (SCALE_F / (float)n) + fcb[0];
  }
}

// ---------------------------------------------------------------------------
extern "C" void kernel_launch(void* const* d_in, const int* in_sizes, int n_in,
                              void* d_out, int out_size, void* d_ws, size_t ws_size,
                              hipStream_t stream) {
  const float* x = (const float*)d_in[0];
  const float* y = (const float*)d_in[1];
  const void* mask = d_in[2];
  const float* W = (const float*)d_in[3];
  const float* fcw = (const float*)d_in[4];
  const float* fcb = (const float*)d_in[5];
  float* out = (float*)d_out;
  char* ws = (char*)d_ws;

  unsigned short* cv = (unsigned short*)ws;                  // [16][1024][512] bf16 = 16 MB
  unsigned short* Wb = (unsigned short*)(ws + (16u << 20));  // [512][512] bf16
  char* st = ws + (16u << 20) + (1u << 19);
  float* sim = (float*)st;                        // 64 f32
  unsigned int* cnt = (unsigned int*)(st + 256);  // 8 u32
  int* det = (int*)(st + 288);                    // 2 i32

  hipMemsetAsync(st, 0, 512, stream);
  detect_mask<<<1, 256, 0, stream>>>((const unsigned char*)mask, det);
  cast_w<<<1024, 256, 0, stream>>>(W, Wb);
  conv_fused<<<512, 256, 0, stream>>>(x, y, Wb, cv);
  score_kernel<<<2048, 256, 0, stream>>>(cv, mask, det, sim, cnt);
  finalize<<<1, 64, 0, stream>>>(sim, cnt, fcw, fcb, out);
}

// Round 4
// 207.964 us; speedup vs baseline: 1.9061x; 1.8473x over previous
//
#include <hip/hip_runtime.h>
#include <stdint.h>

#define UU 512
#define NHEAD 8
#define NB 8
#define NXX 1024
#define NYY 1024
#define SCALE_F 0.125f   // 1/sqrt(64)

typedef __bf16 bf16x8 __attribute__((ext_vector_type(8)));
typedef float f32x4 __attribute__((ext_vector_type(4)));
typedef unsigned short us4 __attribute__((ext_vector_type(4)));

__device__ __forceinline__ unsigned short f2bf(float f) {
  union { float f; uint32_t u; } v; v.f = f;
  return (unsigned short)((v.u + 0x7FFFu + ((v.u >> 16) & 1u)) >> 16);
}

// ---------------------------------------------------------------------------
// Mask dtype probe: u8 bool -> nonzero bytes at p%4==1; f32 1.0f -> nonzero at
// p%4==3 only; int32 0/1 -> neither.
__global__ void detect_mask(const unsigned char* __restrict__ m, int* __restrict__ det) {
  int t = threadIdx.x;
  int c1 = 0, c3 = 0;
  for (int q = t; q < 16384; q += 256) {
    c1 |= m[q * 4 + 1];
    c3 |= m[q * 4 + 3];
  }
  if (c1) atomicOr(&det[0], 1);
  if (c3) atomicOr(&det[1], 1);
}

// ---------------------------------------------------------------------------
__global__ void cast_w(const float* __restrict__ W, unsigned short* __restrict__ Wb) {
  int i = blockIdx.x * 256 + threadIdx.x;
  Wb[i] = f2bf(W[i]);
}

// ---------------------------------------------------------------------------
// Fused transpose+cast+GEMM: cv[bz][n][u] = sum_i W[u][i] * src[b][i][n].
// Block owns (bz, 32 n-rows), computes all 512 u. x-tile staged into LDS as
// transposed bf16 with XOR swizzle: elem(n,i) at n*512 + (i ^ ((n&7)<<3)).
__global__ __launch_bounds__(256, 3) void conv_fused(
    const float* __restrict__ x, const float* __restrict__ y,
    const unsigned short* __restrict__ Wb, unsigned short* __restrict__ cv) {
  __shared__ unsigned short bs[32 * 512];  // 32 KB
  int fl = blockIdx.x;
  int bz = fl & 15, nt = fl >> 4;          // nt 0..31
  int b = bz & 7;
  const float* src = (bz >> 3) ? y : x;
  int n0 = nt * 32;
  int t = threadIdx.x;

  {
    int cq = (t & 7) * 4;
    int i2b = (t >> 3) * 2;
    const float* gb = src + (size_t)b * UU * NXX + n0 + cq;
#pragma unroll
    for (int it = 0; it < 8; it++) {
      int i2 = i2b + it * 64;
      float4 va = *(const float4*)(gb + (size_t)i2 * NXX);
      float4 vb = *(const float4*)(gb + (size_t)(i2 + 1) * NXX);
#pragma unroll
      for (int j = 0; j < 4; j++) {
        int n = cq + j;
        unsigned int pk = (unsigned int)f2bf(((const float*)&va)[j])
                        | ((unsigned int)f2bf(((const float*)&vb)[j]) << 16);
        int e = n * 512 + (i2 ^ ((n & 7) << 3));   // even
        *(unsigned int*)&bs[e] = pk;
      }
    }
  }
  __syncthreads();

  int w = t >> 6, l = t & 63;
  int lane_m = l & 15, lane_g = l >> 4;
  int u0 = w * 128;
  f32x4 acc[2][8] = {};
  for (int kb = 0; kb < 16; kb++) {
    int k = kb * 32 + lane_g * 8;
    bf16x8 a[8], bb[2];
#pragma unroll
    for (int tu = 0; tu < 8; tu++)
      a[tu] = *(const bf16x8*)(Wb + (size_t)(u0 + tu * 16 + lane_m) * UU + k);
#pragma unroll
    for (int tn = 0; tn < 2; tn++) {
      int nl = tn * 16 + lane_m;
      bb[tn] = *(const bf16x8*)&bs[nl * 512 + (k ^ ((nl & 7) << 3))];
    }
#pragma unroll
    for (int tn = 0; tn < 2; tn++)
#pragma unroll
      for (int tu = 0; tu < 8; tu++)
        acc[tn][tu] = __builtin_amdgcn_mfma_f32_16x16x32_bf16(a[tu], bb[tn], acc[tn][tu], 0, 0, 0);
  }
  unsigned short* ob = cv + (size_t)bz * NXX * UU;
#pragma unroll
  for (int tn = 0; tn < 2; tn++)
#pragma unroll
    for (int tu = 0; tu < 8; tu++) {
      int n = n0 + tn * 16 + lane_m;
      int u = u0 + tu * 16 + 4 * lane_g;
      us4 pk;
      pk.x = f2bf(acc[tn][tu][0]); pk.y = f2bf(acc[tn][tu][1]);
      pk.z = f2bf(acc[tn][tu][2]); pk.w = f2bf(acc[tn][tu][3]);
      *(us4*)(ob + (size_t)n * UU + u) = pk;
    }
}

// ---------------------------------------------------------------------------
// Block: (b, 64n, 64m), ALL 8 heads. Wave w: n-half (w&1), head-quad (w>>1).
// Per-block results written NON-atomically to part[block][16] (one 64B line).
__global__ __launch_bounds__(256, 3) void score_kernel(
    const unsigned short* __restrict__ cv, const void* __restrict__ maskp,
    const int* __restrict__ det, float* __restrict__ part) {
  __shared__ float mf[64][68];
  __shared__ float red[4][8];   // per-wave: 4 head partials + count
  int fl = blockIdx.x;
  int b = fl & 7, rr = fl >> 3;
  int nt = rr & 15, mt = rr >> 4;
  int t = threadIdx.x, w = t >> 6, l = t & 63;
  int lane_m = l & 15, lane_g = l >> 4;
  int n0 = nt * 64, m0 = mt * 64;

  int is_u8 = det[0] != 0;   // else 4-byte elems (i32 or f32): nonzero-bits test
  unsigned int cl = 0;
  {
    int row = t >> 2, cq = (t & 3) * 16;
    size_t eb = ((size_t)b * NXX + n0 + row) * NYY + m0 + cq;
    if (is_u8) {
      uint4 v = *(const uint4*)((const unsigned char*)maskp + eb);
#pragma unroll
      for (int j = 0; j < 16; j++) {
        unsigned int word = ((const unsigned int*)&v)[j >> 2];
        int bit = ((word >> ((j & 3) * 8)) & 0xffu) != 0;
        mf[row][cq + j] = (float)bit;
        cl += (unsigned)bit;
      }
    } else {
      const unsigned int* mp = (const unsigned int*)maskp + eb;
#pragma unroll
      for (int q = 0; q < 4; q++) {
        uint4 v = *(const uint4*)(mp + q * 4);
        unsigned int ws[4] = {v.x, v.y, v.z, v.w};
#pragma unroll
        for (int j = 0; j < 4; j++) {
          int bit = ws[j] != 0;
          mf[row][cq + q * 4 + j] = (float)bit;
          cl += (unsigned)bit;
        }
      }
    }
  }
  for (int s = 1; s < 64; s <<= 1) cl += __shfl_xor(cl, s);
  if (l == 0) red[w][4] = (float)cl;
  __syncthreads();

  int nw0 = (w & 1) * 32;
  float mreg[2][4][4];
#pragma unroll
  for (int tn = 0; tn < 2; tn++)
#pragma unroll
    for (int tm = 0; tm < 4; tm++)
#pragma unroll
      for (int r = 0; r < 4; r++)
        mreg[tn][tm][r] = mf[nw0 + tn * 16 + 4 * lane_g + r][tm * 16 + lane_m];

  const unsigned short* xb = cv + ((size_t)b * NXX + n0 + nw0) * UU;
  const unsigned short* yb = cv + ((size_t)(NB + b) * NYY + m0) * UU;
  float hsv[4] = {0.f, 0.f, 0.f, 0.f};
#pragma unroll
  for (int hh = 0; hh < 4; hh++) {
    int co = ((w >> 1) * 4 + hh) * 64;
    bf16x8 afr[2][2], bfr[4][2];
#pragma unroll
    for (int tn = 0; tn < 2; tn++)
#pragma unroll
      for (int kb = 0; kb < 2; kb++)
        afr[tn][kb] = *(const bf16x8*)(xb + (size_t)(tn * 16 + lane_m) * UU + co + kb * 32 + lane_g * 8);
#pragma unroll
    for (int tm = 0; tm < 4; tm++)
#pragma unroll
      for (int kb = 0; kb < 2; kb++)
        bfr[tm][kb] = *(const bf16x8*)(yb + (size_t)(tm * 16 + lane_m) * UU + co + kb * 32 + lane_g * 8);
#pragma unroll
    for (int tn = 0; tn < 2; tn++)
#pragma unroll
      for (int tm = 0; tm < 4; tm++) {
        f32x4 acc = {};
        acc = __builtin_amdgcn_mfma_f32_16x16x32_bf16(afr[tn][0], bfr[tm][0], acc, 0, 0, 0);
        acc = __builtin_amdgcn_mfma_f32_16x16x32_bf16(afr[tn][1], bfr[tm][1], acc, 0, 0, 0);
#pragma unroll
        for (int r = 0; r < 4; r++) {
          float v = acc[r];
          v = v > 0.f ? v : 0.f;
          hsv[hh] = fmaf(v, mreg[tn][tm][r], hsv[hh]);
        }
      }
  }
#pragma unroll
  for (int hh = 0; hh < 4; hh++) {
    float hs = hsv[hh];
    for (int s = 1; s < 64; s <<= 1) hs += __shfl_xor(hs, s);
    if (l == 0) red[w][hh] = hs;
  }
  __syncthreads();
  float* pb = part + (size_t)fl * 16;
  if (t < 8) {
    int q = t >> 2, hh = t & 3;            // head t computed by waves q*2, q*2+1
    pb[t] = red[q * 2][hh] + red[q * 2 + 1][hh];
  } else if (t == 8) {
    pb[8] = red[0][4] + red[1][4] + red[2][4] + red[3][4];
  }
}

// ---------------------------------------------------------------------------
// One block per b: reduce part[b*256 .. b*256+255][0..8] -> out[b].
__global__ __launch_bounds__(256) void finalize(
    const float* __restrict__ part, const float* __restrict__ fcw,
    const float* __restrict__ fcb, float* __restrict__ out) {
  __shared__ float red[4][9];
  int b = blockIdx.x;
  int t = threadIdx.x, w = t >> 6, l = t & 63;
  const float* pb = part + (size_t)(b * 256 + t) * 16;
  float v[9];
#pragma unroll
  for (int j = 0; j < 9; j++) v[j] = pb[j];
#pragma unroll
  for (int j = 0; j < 9; j++) {
    float s = v[j];
    for (int ss = 1; ss < 64; ss <<= 1) s += __shfl_xor(s, ss);
    v[j] = s;
  }
  if (l == 0)
#pragma unroll
    for (int j = 0; j < 9; j++) red[w][j] = v[j];
  __syncthreads();
  if (t == 0) {
    float s = 0.f, cn = 0.f;
#pragma unroll
    for (int h = 0; h < NHEAD; h++)
      s += (red[0][h] + red[1][h] + red[2][h] + red[3][h]) * fcw[h];
    cn = red[0][8] + red[1][8] + red[2][8] + red[3][8];
    if (cn < 0.5f) cn = 1.f;
    out[b] = s * (SCALE_F / cn) + fcb[0];
  }
}

// ---------------------------------------------------------------------------
extern "C" void kernel_launch(void* const* d_in, const int* in_sizes, int n_in,
                              void* d_out, int out_size, void* d_ws, size_t ws_size,
                              hipStream_t stream) {
  const float* x = (const float*)d_in[0];
  const float* y = (const float*)d_in[1];
  const void* mask = d_in[2];
  const float* W = (const float*)d_in[3];
  const float* fcw = (const float*)d_in[4];
  const float* fcb = (const float*)d_in[5];
  float* out = (float*)d_out;
  char* ws = (char*)d_ws;

  unsigned short* cv = (unsigned short*)ws;                  // [16][1024][512] bf16 = 16 MB
  unsigned short* Wb = (unsigned short*)(ws + (16u << 20));  // [512][512] bf16 = 512 KB
  float* part = (float*)(ws + (16u << 20) + (1u << 19));     // [2048][16] f32 = 128 KB
  char* st = ws + (16u << 20) + (1u << 19) + (1u << 17);
  int* det = (int*)st;                                        // 2 i32

  hipMemsetAsync(st, 0, 64, stream);
  detect_mask<<<1, 256, 0, stream>>>((const unsigned char*)mask, det);
  cast_w<<<1024, 256, 0, stream>>>(W, Wb);
  conv_fused<<<512, 256, 0, stream>>>(x, y, Wb, cv);
  score_kernel<<<2048, 256, 0, stream>>>(cv, mask, det, part);
  finalize<<<NB, 256, 0, stream>>>(part, fcw, fcb, out);
}

// Round 5
// 166.115 us; speedup vs baseline: 2.3863x; 1.2519x over previous
//
#include <hip/hip_runtime.h>
#include <stdint.h>

#define UU 512
#define NHEAD 8
#define NB 8
#define NXX 1024
#define NYY 1024
#define SCALE_F 0.125f   // 1/sqrt(64)

typedef __bf16 bf16x8 __attribute__((ext_vector_type(8)));
typedef float f32x4 __attribute__((ext_vector_type(4)));
typedef unsigned short us4 __attribute__((ext_vector_type(4)));

__device__ __forceinline__ unsigned short f2bf(float f) {
  union { float f; uint32_t u; } v; v.f = f;
  return (unsigned short)((v.u + 0x7FFFu + ((v.u >> 16) & 1u)) >> 16);
}

// ---------------------------------------------------------------------------
// prep: blocks 0..1023 cast W->bf16; blocks 1024..1039 probe mask dtype.
// u8 bool -> nonzero bytes at p%4==1; i32/f32 -> zero there.
__global__ void prep_kernel(const float* __restrict__ W, unsigned short* __restrict__ Wb,
                            const unsigned char* __restrict__ m, int* __restrict__ det) {
  int blk = blockIdx.x, t = threadIdx.x;
  if (blk < 1024) {
    int i = blk * 256 + t;
    Wb[i] = f2bf(W[i]);
  } else {
    int idx = ((blk - 1024) * 256 + t) * 16;   // 16 blocks x 256 x 16B = 64KB
    uint4 v = *(const uint4*)(m + idx);
    unsigned int c1 = (v.x & 0xff00u) | (v.y & 0xff00u) | (v.z & 0xff00u) | (v.w & 0xff00u);
    if (c1) atomicOr(&det[0], 1);
  }
}

// ---------------------------------------------------------------------------
// Fused transpose+cast+GEMM: cv[bz][n][u] = sum_i W[u][i] * src[b][i][n].
// Block owns (bz, 32 n-rows), all 512 u. x staged to LDS transposed bf16,
// XOR swizzle elem(n,i) at n*512 + (i ^ ((n&7)<<3)). kb-loop double-buffered.
__global__ __launch_bounds__(256, 2) void conv_fused(
    const float* __restrict__ x, const float* __restrict__ y,
    const unsigned short* __restrict__ Wb, unsigned short* __restrict__ cv) {
  __shared__ unsigned short bs[32 * 512];  // 32 KB
  int fl = blockIdx.x;
  int bz = fl & 15, nt = fl >> 4;          // nt 0..31
  int b = bz & 7;
  const float* src = (bz >> 3) ? y : x;
  int n0 = nt * 32;
  int t = threadIdx.x;

  {
    int cq = (t & 7) * 4;
    int i2b = (t >> 3) * 2;
    const float* gb = src + (size_t)b * UU * NXX + n0 + cq;
#pragma unroll
    for (int it = 0; it < 8; it++) {
      int i2 = i2b + it * 64;
      float4 va = *(const float4*)(gb + (size_t)i2 * NXX);
      float4 vb = *(const float4*)(gb + (size_t)(i2 + 1) * NXX);
#pragma unroll
      for (int j = 0; j < 4; j++) {
        int n = cq + j;
        unsigned int pk = (unsigned int)f2bf(((const float*)&va)[j])
                        | ((unsigned int)f2bf(((const float*)&vb)[j]) << 16);
        int e = n * 512 + (i2 ^ ((n & 7) << 3));
        *(unsigned int*)&bs[e] = pk;
      }
    }
  }
  __syncthreads();

  int w = t >> 6, l = t & 63;
  int lane_m = l & 15, lane_g = l >> 4;
  int u0 = w * 128;
  f32x4 acc[2][8] = {};
  bf16x8 aA[8], aB[8], bA[2], bB[2];

#define LOADW(Adst, Bdst, KB) do {                                            \
    int k_ = (KB) * 32 + lane_g * 8;                                          \
    _Pragma("unroll") for (int tu = 0; tu < 8; tu++)                          \
      Adst[tu] = *(const bf16x8*)(Wb + (size_t)(u0 + tu * 16 + lane_m) * UU + k_); \
    _Pragma("unroll") for (int tn = 0; tn < 2; tn++) {                        \
      int nl_ = tn * 16 + lane_m;                                             \
      Bdst[tn] = *(const bf16x8*)&bs[nl_ * 512 + (k_ ^ ((nl_ & 7) << 3))];    \
    }                                                                         \
  } while (0)
#define DOMFMA(Ab, Bb) do {                                                   \
    _Pragma("unroll") for (int tn = 0; tn < 2; tn++)                          \
    _Pragma("unroll") for (int tu = 0; tu < 8; tu++)                          \
      acc[tn][tu] = __builtin_amdgcn_mfma_f32_16x16x32_bf16(Ab[tu], Bb[tn], acc[tn][tu], 0, 0, 0); \
  } while (0)

  LOADW(aA, bA, 0);
#pragma unroll
  for (int kp = 0; kp < 8; kp++) {
    LOADW(aB, bB, 2 * kp + 1);
    DOMFMA(aA, bA);
    if (kp < 7) LOADW(aA, bA, 2 * kp + 2);
    DOMFMA(aB, bB);
  }
#undef LOADW
#undef DOMFMA

  unsigned short* ob = cv + (size_t)bz * NXX * UU;
#pragma unroll
  for (int tn = 0; tn < 2; tn++)
#pragma unroll
    for (int tu = 0; tu < 8; tu++) {
      int n = n0 + tn * 16 + lane_m;
      int u = u0 + tu * 16 + 4 * lane_g;
      us4 pk;
      pk.x = f2bf(acc[tn][tu][0]); pk.y = f2bf(acc[tn][tu][1]);
      pk.z = f2bf(acc[tn][tu][2]); pk.w = f2bf(acc[tn][tu][3]);
      *(us4*)(ob + (size_t)n * UU + u) = pk;
    }
}

// ---------------------------------------------------------------------------
// Block: (b, 64n, 64m), all 8 heads, 4 waves. x-frags hoisted to regs (issued
// first), y-tile 64x512 staged to LDS coalesced w/ granule-XOR swizzle, mask
// staged as bf16. Inner loop per head: 8 ds_read_b128 + 16 MFMA.
__global__ __launch_bounds__(256, 2) void score_kernel(
    const unsigned short* __restrict__ cv, const void* __restrict__ maskp,
    const int* __restrict__ det, float* __restrict__ part) {
  __shared__ unsigned short ys[64 * 512];    // 64 KB
  __shared__ unsigned short mf16[64][72];    // 9.2 KB bf16 0/1
  __shared__ float red[4][8];
  int fl = blockIdx.x;
  int b = fl & 7, rr = fl >> 3;
  int nt = rr & 15, mt = rr >> 4;
  int t = threadIdx.x, w = t >> 6, l = t & 63;
  int lane_m = l & 15, lane_g = l >> 4;
  int n0 = nt * 64, m0 = mt * 64;
  int nw0 = (w & 1) * 32, hq = (w >> 1) * 4;

  // ---- x-side frags for all 4 heads: issue before staging (latency hidden)
  const unsigned short* xb = cv + ((size_t)b * NXX + n0 + nw0) * UU;
  bf16x8 afr[4][2][2];
#pragma unroll
  for (int hh = 0; hh < 4; hh++) {
    int co = (hq + hh) * 64;
#pragma unroll
    for (int tn = 0; tn < 2; tn++)
#pragma unroll
      for (int kb = 0; kb < 2; kb++)
        afr[hh][tn][kb] = *(const bf16x8*)(xb + (size_t)(tn * 16 + lane_m) * UU + co + kb * 32 + lane_g * 8);
  }

  // ---- stage y tile (64 rows x 512) into LDS, granule-XOR swizzle
  const unsigned short* yb = cv + ((size_t)(NB + b) * NYY + m0) * UU;
  {
    int seg = t & 63;
#pragma unroll
    for (int p = 0; p < 16; p++) {
      int r2 = p * 4 + (t >> 6);
      uint4 v = *(const uint4*)(yb + (size_t)r2 * UU + seg * 8);
      int sp = seg ^ (r2 & 7);
      *(uint4*)&ys[r2 * 512 + sp * 8] = v;
    }
  }

  // ---- mask -> mf16 (bf16 0/1) + count
  int is_u8 = det[0] != 0;
  unsigned int cl = 0;
  {
    int row = t >> 2, cq = (t & 3) * 16;
    size_t eb = ((size_t)b * NXX + n0 + row) * NYY + m0 + cq;
    if (is_u8) {
      uint4 v = *(const uint4*)((const unsigned char*)maskp + eb);
#pragma unroll
      for (int j = 0; j < 16; j++) {
        unsigned int word = ((const unsigned int*)&v)[j >> 2];
        int bit = ((word >> ((j & 3) * 8)) & 0xffu) != 0;
        mf16[row][cq + j] = bit ? 0x3F80u : 0u;
        cl += (unsigned)bit;
      }
    } else {
      const unsigned int* mp = (const unsigned int*)maskp + eb;
#pragma unroll
      for (int q = 0; q < 4; q++) {
        uint4 v = *(const uint4*)(mp + q * 4);
        unsigned int wds[4] = {v.x, v.y, v.z, v.w};
#pragma unroll
        for (int j = 0; j < 4; j++) {
          int bit = wds[j] != 0;
          mf16[row][cq + q * 4 + j] = bit ? 0x3F80u : 0u;
          cl += (unsigned)bit;
        }
      }
    }
  }
  for (int s = 1; s < 64; s <<= 1) cl += __shfl_xor(cl, s);
  if (l == 0) red[w][4] = (float)cl;
  __syncthreads();

  // ---- mask frags to regs (2-way LDS aliasing only)
  float mreg[2][4][4];
#pragma unroll
  for (int tn = 0; tn < 2; tn++)
#pragma unroll
    for (int tm = 0; tm < 4; tm++)
#pragma unroll
      for (int r = 0; r < 4; r++) {
        unsigned int u = (unsigned int)mf16[nw0 + tn * 16 + 4 * lane_g + r][tm * 16 + lane_m] << 16;
        union { unsigned int u; float f; } cvt; cvt.u = u;
        mreg[tn][tm][r] = cvt.f;
      }

  // ---- per-head: y frags from LDS, MFMA, fused relu*mask accumulate
  float hsv[4] = {0.f, 0.f, 0.f, 0.f};
#pragma unroll
  for (int hh = 0; hh < 4; hh++) {
    int segbase = (hq + hh) * 8;            // head chunk = 8 granules
    bf16x8 bfr[4][2];
#pragma unroll
    for (int tm = 0; tm < 4; tm++) {
      int row = tm * 16 + lane_m;
#pragma unroll
      for (int kb = 0; kb < 2; kb++) {
        int sp = (segbase + kb * 4 + lane_g) ^ (row & 7);
        bfr[tm][kb] = *(const bf16x8*)&ys[row * 512 + sp * 8];
      }
    }
#pragma unroll
    for (int tn = 0; tn < 2; tn++)
#pragma unroll
      for (int tm = 0; tm < 4; tm++) {
        f32x4 acc = {};
        acc = __builtin_amdgcn_mfma_f32_16x16x32_bf16(afr[hh][tn][0], bfr[tm][0], acc, 0, 0, 0);
        acc = __builtin_amdgcn_mfma_f32_16x16x32_bf16(afr[hh][tn][1], bfr[tm][1], acc, 0, 0, 0);
#pragma unroll
        for (int r = 0; r < 4; r++) {
          float v = acc[r];
          v = v > 0.f ? v : 0.f;
          hsv[hh] = fmaf(v, mreg[tn][tm][r], hsv[hh]);
        }
      }
  }
#pragma unroll
  for (int hh = 0; hh < 4; hh++) {
    float hs = hsv[hh];
    for (int s = 1; s < 64; s <<= 1) hs += __shfl_xor(hs, s);
    if (l == 0) red[w][hh] = hs;
  }
  __syncthreads();
  float* pb = part + (size_t)fl * 16;
  if (t < 8) {
    int q = t >> 2, hh = t & 3;
    pb[t] = red[q * 2][hh] + red[q * 2 + 1][hh];
  } else if (t == 8) {
    pb[8] = red[0][4] + red[1][4] + red[2][4] + red[3][4];
  }
}

// ---------------------------------------------------------------------------
// One block per b. Batch b's score blocks are fl = j*8 + b (fl&7==b), j=0..255.
__global__ __launch_bounds__(256) void finalize(
    const float* __restrict__ part, const float* __restrict__ fcw,
    const float* __restrict__ fcb, float* __restrict__ out) {
  __shared__ float red[4][9];
  int b = blockIdx.x;
  int t = threadIdx.x, w = t >> 6, l = t & 63;
  const float* pb = part + (size_t)(t * 8 + b) * 16;   // row fl = t*8+b
  float v[9];
#pragma unroll
  for (int j = 0; j < 9; j++) v[j] = pb[j];
#pragma unroll
  for (int j = 0; j < 9; j++) {
    float s = v[j];
    for (int ss = 1; ss < 64; ss <<= 1) s += __shfl_xor(s, ss);
    v[j] = s;
  }
  if (l == 0)
#pragma unroll
    for (int j = 0; j < 9; j++) red[w][j] = v[j];
  __syncthreads();
  if (t == 0) {
    float s = 0.f, cn = 0.f;
#pragma unroll
    for (int h = 0; h < NHEAD; h++)
      s += (red[0][h] + red[1][h] + red[2][h] + red[3][h]) * fcw[h];
    cn = red[0][8] + red[1][8] + red[2][8] + red[3][8];
    if (cn < 0.5f) cn = 1.f;
    out[b] = s * (SCALE_F / cn) + fcb[0];
  }
}

// ---------------------------------------------------------------------------
extern "C" void kernel_launch(void* const* d_in, const int* in_sizes, int n_in,
                              void* d_out, int out_size, void* d_ws, size_t ws_size,
                              hipStream_t stream) {
  const float* x = (const float*)d_in[0];
  const float* y = (const float*)d_in[1];
  const void* mask = d_in[2];
  const float* W = (const float*)d_in[3];
  const float* fcw = (const float*)d_in[4];
  const float* fcb = (const float*)d_in[5];
  float* out = (float*)d_out;
  char* ws = (char*)d_ws;

  unsigned short* cv = (unsigned short*)ws;                  // [16][1024][512] bf16 = 16 MB
  unsigned short* Wb = (unsigned short*)(ws + (16u << 20));  // [512][512] bf16 = 512 KB
  float* part = (float*)(ws + (16u << 20) + (1u << 19));     // [2048][16] f32 = 128 KB
  char* st = ws + (16u << 20) + (1u << 19) + (1u << 17);
  int* det = (int*)st;                                        // 1 i32

  hipMemsetAsync(st, 0, 64, stream);
  prep_kernel<<<1040, 256, 0, stream>>>(W, Wb, (const unsigned char*)mask, det);
  conv_fused<<<512, 256, 0, stream>>>(x, y, Wb, cv);
  score_kernel<<<2048, 256, 0, stream>>>(cv, mask, det, part);
  finalize<<<NB, 256, 0, stream>>>(part, fcw, fcb, out);
}